// Round 13
// baseline (139.821 us; speedup 1.0000x reference)
//
#include <hip/hip_runtime.h>

#define N_NODES 100000
#define N_EDGES 1000000
#define D 64
#define NCLS 10
#define NTILES (N_NODES / 16)   // 6250, exact

#define NBUCK 196            // buckets of 512 nodes: bucket = dst >> 9
#define BNODES 512
#define P_BLOCKS 256         // partition blocks
#define P_EPB 3907           // edges per partition block; 256*3907 >= 1M

#define CVT_BLOCKS (N_NODES * D / 4 / 256)   // 6250, exact

typedef __attribute__((ext_vector_type(8))) short bf16x8;   // 8 bf16 = 4 VGPR
typedef __attribute__((ext_vector_type(4))) float f32x4;

// round-to-nearest-even f32 -> bf16 bits
__device__ __forceinline__ unsigned short f2bf(float x) {
    unsigned int u = __float_as_uint(x);
    u += 0x7fffu + ((u >> 16) & 1u);
    return (unsigned short)(u >> 16);
}
__device__ __forceinline__ unsigned int pack2bf(float lo, float hi) {
    return (unsigned int)f2bf(lo) | ((unsigned int)f2bf(hi) << 16);
}
__device__ __forceinline__ float blo(unsigned int u) { return __uint_as_float(u << 16); }
__device__ __forceinline__ float bhi(unsigned int u) { return __uint_as_float(u & 0xffff0000u); }

// ---------------------------------------------------------------------------
// Kernel 1 (merged): blocks 0..255 -> per-(block,bucket) edge histogram;
// then prep blocks (bf16 table + weight packs); last block zeroes the
// sentinel row N_NODES of both feature tables (zero-row gather trick).
// ---------------------------------------------------------------------------
__global__ __launch_bounds__(256) void hist_prep(const int* __restrict__ dst,
                                                 int* __restrict__ histG,
                                                 const float* __restrict__ x,
                                                 const float* __restrict__ W1l,
                                                 const float* __restrict__ W1r,
                                                 const float* __restrict__ W2l,
                                                 const float* __restrict__ W2r,
                                                 const float* __restrict__ Wout,
                                                 unsigned short* __restrict__ xb,
                                                 unsigned short* __restrict__ h1b,
                                                 unsigned int* __restrict__ pB1,
                                                 unsigned int* __restrict__ pB2,
                                                 unsigned int* __restrict__ pBo) {
    const int tid = threadIdx.x;
    if (blockIdx.x < P_BLOCKS) {                 // ---- edge histogram ----
        __shared__ int lh[256];
        lh[tid] = 0;
        __syncthreads();
        const int e0 = blockIdx.x * P_EPB;
        int ecnt = N_EDGES - e0;
        if (ecnt > P_EPB) ecnt = P_EPB;
        if (ecnt < 0) ecnt = 0;
        for (int i = tid; i < ecnt; i += 256)
            atomicAdd(&lh[dst[e0 + i] >> 9], 1);   // LDS atomic
        __syncthreads();
        if (tid < NBUCK) histG[tid * P_BLOCKS + blockIdx.x] = lh[tid];
        return;
    }
    const int b = blockIdx.x - P_BLOCKS;
    if (b < CVT_BLOCKS) {                        // ---- x -> bf16 table ----
        int i = b * 256 + tid;                   // float4 index, exact bound
        float4 v = ((const float4*)x)[i];
        ushort4 o;
        o.x = f2bf(v.x); o.y = f2bf(v.y); o.z = f2bf(v.z); o.w = f2bf(v.w);
        ((ushort4*)xb)[i] = o;
    } else if (b < CVT_BLOCKS + 32) {            // ---- SAGE weight packs ----
        int wsel = (b - CVT_BLOCKS) >> 4;
        const float* Wl = wsel ? W2l : W1l;
        const float* Wr = wsel ? W2r : W1r;
        unsigned int* pB = wsel ? pB2 : pB1;
        int idx = ((b - CVT_BLOCKS) & 15) * 256 + tid;   // 0..4095
        int r    = idx & 3;
        int lane = (idx >> 2) & 63;
        int n    = (idx >> 8) & 3;
        int t    = idx >> 10;
        int j  = n * 16 + (lane & 15);
        int k0 = t * 32 + ((lane >> 4) << 3) + 2 * r;
        float lo = (k0 < 64) ? Wl[j * 64 + k0] : Wr[j * 64 + (k0 - 64)];
        float hi = (k0 + 1 < 64) ? Wl[j * 64 + k0 + 1] : Wr[j * 64 + (k0 - 63)];
        pB[idx] = pack2bf(lo, hi);
    } else if (b < CVT_BLOCKS + 34) {            // ---- W_out pack ----
        int idx = (b - CVT_BLOCKS - 32) * 256 + tid;
        if (idx < 512) {
            int r    = idx & 3;
            int lane = (idx >> 2) & 63;
            int t    = idx >> 8;
            int j  = lane & 15;
            int k0 = t * 32 + ((lane >> 4) << 3) + 2 * r;
            float lo = (j < NCLS) ? Wout[j * 64 + k0] : 0.f;
            float hi = (j < NCLS) ? Wout[j * 64 + k0 + 1] : 0.f;
            pBo[idx] = pack2bf(lo, hi);
        }
    } else {                                     // ---- zero sentinel rows ----
        if (tid < 64) {
            xb[N_NODES * 64 + tid] = 0;
            h1b[N_NODES * 64 + tid] = 0;
        }
    }
}

// ---------------------------------------------------------------------------
// Kernel 2: per-256-chunk sums of histG rows (196 blocks).
// ---------------------------------------------------------------------------
__global__ __launch_bounds__(256) void scan_partials(const int* __restrict__ in,
                                                     int* __restrict__ blockSum) {
    __shared__ int s[256];
    s[threadIdx.x] = in[blockIdx.x * 256 + threadIdx.x];
    __syncthreads();
    for (int st = 128; st > 0; st >>= 1) {
        if (threadIdx.x < st) s[threadIdx.x] += s[threadIdx.x + st];
        __syncthreads();
    }
    if (threadIdx.x == 0) blockSum[blockIdx.x] = s[0];
}

// ---------------------------------------------------------------------------
// Kernel 3: full exclusive scan -> ebase (each block re-scans 196 row totals).
// ---------------------------------------------------------------------------
__global__ __launch_bounds__(256) void scan_final(const int* __restrict__ in,
                                                  const int* __restrict__ blockSum,
                                                  int* __restrict__ ebase) {
    __shared__ int p[256];
    __shared__ int s[256];
    const int t = threadIdx.x;
    int pv = (t < NBUCK) ? blockSum[t] : 0;
    p[t] = pv;
    __syncthreads();
    for (int st = 1; st < 256; st <<= 1) {
        int u = (t >= st) ? p[t - st] : 0;
        __syncthreads();
        p[t] += u;
        __syncthreads();
    }
    const int rowOff = (blockIdx.x > 0) ? p[blockIdx.x - 1] : 0;
    const int i = blockIdx.x * 256 + t;
    int v = in[i];
    s[t] = v;
    __syncthreads();
    for (int st = 1; st < 256; st <<= 1) {
        int u = (t >= st) ? s[t - st] : 0;
        __syncthreads();
        s[t] += u;
        __syncthreads();
    }
    ebase[i] = s[t] - v + rowOff;
}

// ---------------------------------------------------------------------------
// Kernel 4: partition edges into bucket-sorted packed array.
// Packed record: (src<<9)|(dst&511).
// ---------------------------------------------------------------------------
__global__ __launch_bounds__(256) void edge_partition(const int* __restrict__ src,
                                                      const int* __restrict__ dst,
                                                      const int* __restrict__ ebase,
                                                      unsigned int* __restrict__ pairs) {
    __shared__ int s[256];
    __shared__ int lbase[256];
    __shared__ int lcur[256];
    __shared__ uint2 buf[P_EPB];     // 31.2 KB
    const int tid = threadIdx.x;
    const int e0 = blockIdx.x * P_EPB;
    int ecnt = N_EDGES - e0;
    if (ecnt > P_EPB) ecnt = P_EPB;
    if (ecnt < 0) ecnt = 0;

    lcur[tid] = 0;
    __syncthreads();
    for (int i = tid; i < ecnt; i += 256)
        atomicAdd(&lcur[dst[e0 + i] >> 9], 1);
    __syncthreads();
    int v = lcur[tid];
    s[tid] = v;
    __syncthreads();
    for (int st = 1; st < 256; st <<= 1) {
        int u = (tid >= st) ? s[tid - st] : 0;
        __syncthreads();
        s[tid] += u;
        __syncthreads();
    }
    int excl = s[tid] - v;
    lbase[tid] = excl;
    lcur[tid] = excl;
    __syncthreads();
    for (int i = tid; i < ecnt; i += 256) {
        int d = dst[e0 + i], sv = src[e0 + i];
        int p = atomicAdd(&lcur[d >> 9], 1);
        buf[p] = make_uint2((unsigned)sv, (unsigned)d);
    }
    __syncthreads();
    for (int i = tid; i < ecnt; i += 256) {
        uint2 pr = buf[i];
        int bk = (int)(pr.y >> 9);
        pairs[ebase[bk * P_BLOCKS + blockIdx.x] + (i - lbase[bk])] =
            (pr.x << 9) | (pr.y & 511u);
    }
}

// ---------------------------------------------------------------------------
// Kernel 5: per-bucket node hist + scan -> row_ptr; LDS-cursor scatter of
// src into sorted_src.
// ---------------------------------------------------------------------------
__global__ __launch_bounds__(256) void bucket_csr(const unsigned int* __restrict__ pairs,
                                                  const int* __restrict__ ebase,
                                                  int* __restrict__ row_ptr,
                                                  int* __restrict__ sorted_src) {
    __shared__ int h[BNODES];    // counts -> exclusive scan -> cursors
    __shared__ int part[256];
    const int tid = threadIdx.x;
    const int b = blockIdx.x;
    const int base = ebase[b * P_BLOCKS];
    const int next = (b == NBUCK - 1) ? N_EDGES : ebase[(b + 1) * P_BLOCKS];
    const int cnt = next - base;
    const int n0 = b * BNODES;

    h[tid] = 0; h[tid + 256] = 0;
    __syncthreads();
    for (int i = tid; i < cnt; i += 256)
        atomicAdd(&h[pairs[base + i] & 511u], 1);
    __syncthreads();
    int a0 = h[2 * tid], a1 = h[2 * tid + 1];
    part[tid] = a0 + a1;
    __syncthreads();
    for (int st = 1; st < 256; st <<= 1) {
        int u = (tid >= st) ? part[tid - st] : 0;
        __syncthreads();
        part[tid] += u;
        __syncthreads();
    }
    int eb = part[tid] - (a0 + a1);          // exclusive base of node pair
    h[2 * tid] = eb;
    h[2 * tid + 1] = eb + a0;
    int node0 = n0 + 2 * tid;
    if (node0 <= N_NODES) row_ptr[node0] = base + eb;
    if (node0 + 1 <= N_NODES) row_ptr[node0 + 1] = base + eb + a0;
    __syncthreads();
    for (int i = tid; i < cnt; i += 256) {
        unsigned int pr = pairs[base + i];
        int p = atomicAdd(&h[pr & 511u], 1);
        sorted_src[base + p] = (int)(pr >> 9);
    }
}

// ---------------------------------------------------------------------------
// Gather helpers. 16 lanes x dwordx2 (8B) per row => 4 edge slots; only a
// 2-round butterfly per node (vs 3 with 8 slots) -> 3x less reduce VALU.
// Invalid slots redirect INDEX to the zero sentinel row.
// ---------------------------------------------------------------------------
__device__ __forceinline__ void grow2(float& a0, float& a1, float& a2, float& a3,
                                      const uint2* __restrict__ featb2,
                                      const int* __restrict__ sorted_src,
                                      int ei, int end, int q) {
    int sv = sorted_src[ei];            // may over-read within ws; benign
    int ix = (ei < end) ? sv : N_NODES; // sentinel row = zeros
    uint2 v = featb2[ix * 16 + q];
    a0 += blo(v.x); a1 += bhi(v.x);
    a2 += blo(v.y); a3 += bhi(v.y);
}

// One wave gathers 4 nodes' mean rows into the block-shared LDS tile.
__device__ __forceinline__ void gather4(
        const uint2* __restrict__ featb2,   // bf16 rows as [N][16] uint2
        const int* __restrict__ row_ptr,
        const int* __restrict__ sorted_src,
        int node0, int l, unsigned short mt[16][72], int mrow0) {
    const int q = l & 15;       // row eighth (8B = feats 4q..4q+3)
    const int e = l >> 4;       // edge slot 0..3

    int rp = 0;
    if (l <= 4) rp = row_ptr[node0 + l];   // 5 boundaries

    for (int r = 0; r < 4; ++r) {
        const int start = __shfl(rp, r);
        const int end   = __shfl(rp, r + 1);
        const int deg   = end - start;

        float a0 = 0.f, a1 = 0.f, a2 = 0.f, a3 = 0.f;
        for (int base = 0; base < deg; base += 16) {   // wave-uniform branches
            const int rm = deg - base;
            const int i0 = start + base + e;
            grow2(a0, a1, a2, a3, featb2, sorted_src, i0, end, q);
            if (rm > 4)  grow2(a0, a1, a2, a3, featb2, sorted_src, i0 + 4, end, q);
            if (rm > 8)  grow2(a0, a1, a2, a3, featb2, sorted_src, i0 + 8, end, q);
            if (rm > 12) grow2(a0, a1, a2, a3, featb2, sorted_src, i0 + 12, end, q);
        }
        // reduce over the 4 edge slots (lane bits 4,5): 2 rounds x 4 accums
        a0 += __shfl_xor(a0, 16); a1 += __shfl_xor(a1, 16);
        a2 += __shfl_xor(a2, 16); a3 += __shfl_xor(a3, 16);
        a0 += __shfl_xor(a0, 32); a1 += __shfl_xor(a1, 32);
        a2 += __shfl_xor(a2, 32); a3 += __shfl_xor(a3, 32);
        if (e == 0) {
            float inv = 1.0f / fmaxf((float)deg, 1.0f);
            uint2 o;
            o.x = pack2bf(a0 * inv, a1 * inv);
            o.y = pack2bf(a2 * inv, a3 * inv);
            *(uint2*)&mt[mrow0 + r][q << 2] = o;   // 8B, 16 lanes -> 128B row
        }
    }
}

// ---------------------------------------------------------------------------
// Layer 1 fused: 1 tile per block, 4 waves. Each wave gathers 4 nodes ->
// sync -> each wave runs ONE N-tile MFMA chain (4 MFMAs) and stores 16 cols.
// ---------------------------------------------------------------------------
__global__ __launch_bounds__(256) void sage_fused(
        const uint2* __restrict__ featb2,          // xb (with zero row)
        const int* __restrict__ row_ptr,
        const int* __restrict__ sorted_src,
        const unsigned int* __restrict__ packedB,
        const float* __restrict__ bias,
        unsigned short* __restrict__ outb) {
    __shared__ __align__(16) unsigned short mt[16][72];
    const int wv = threadIdx.x >> 6;
    const int l  = threadIdx.x & 63;
    const int tile = blockIdx.x;               // grid exact (NTILES blocks)

    gather4(featb2, row_ptr, sorted_src, (tile << 4) + (wv << 2), l, mt, wv << 2);
    __syncthreads();

    const int col = l & 15;
    const int g   = l >> 4;
    bf16x8 af0 = *(const bf16x8*)&mt[col][g << 3];
    bf16x8 af1 = *(const bf16x8*)&mt[col][32 + (g << 3)];
    const unsigned int* srw = (const unsigned int*)featb2 + ((tile << 4) + col) * 32;
    bf16x8 af2 = *(const bf16x8*)(srw + (g << 2));
    bf16x8 af3 = *(const bf16x8*)(srw + 16 + (g << 2));

    const int n = wv;                          // one N-tile per wave
    bf16x8 b0 = *(const bf16x8*)(packedB + (((0 * 4 + n) * 64 + l) << 2));
    bf16x8 b1 = *(const bf16x8*)(packedB + (((1 * 4 + n) * 64 + l) << 2));
    bf16x8 b2 = *(const bf16x8*)(packedB + (((2 * 4 + n) * 64 + l) << 2));
    bf16x8 b3 = *(const bf16x8*)(packedB + (((3 * 4 + n) * 64 + l) << 2));
    f32x4 a = {0.f, 0.f, 0.f, 0.f};
    a = __builtin_amdgcn_mfma_f32_16x16x32_bf16(af0, b0, a, 0, 0, 0);
    a = __builtin_amdgcn_mfma_f32_16x16x32_bf16(af1, b1, a, 0, 0, 0);
    a = __builtin_amdgcn_mfma_f32_16x16x32_bf16(af2, b2, a, 0, 0, 0);
    a = __builtin_amdgcn_mfma_f32_16x16x32_bf16(af3, b3, a, 0, 0, 0);

    const int j = (n << 4) | col;
    const float bj = bias[j];
#pragma unroll
    for (int r = 0; r < 4; ++r) {
        int node = (tile << 4) + (g << 2) + r;
        outb[node * 64 + j] = f2bf(fmaxf(a[r] + bj, 0.f));
    }
}

// ---------------------------------------------------------------------------
// Layer 2 fused + output projection: same structure; h2 tile assembled in
// LDS (each wave writes its 16-col slice), then wave 0 runs the K=64
// projection MFMAs. No h2 buffer.
// ---------------------------------------------------------------------------
__global__ __launch_bounds__(256) void sage_fused_out(
        const uint2* __restrict__ featb2,           // h1b (with zero row)
        const int* __restrict__ row_ptr,
        const int* __restrict__ sorted_src,
        const unsigned int* __restrict__ packedB,   // layer-2 weights
        const float* __restrict__ bias,             // b2
        const unsigned int* __restrict__ packedBo,  // 512 dwords
        const float* __restrict__ bout,
        float* __restrict__ out) {
    __shared__ __align__(16) unsigned short mt[16][72];
    __shared__ __align__(16) unsigned short ht[16][72];
    const int wv = threadIdx.x >> 6;
    const int l  = threadIdx.x & 63;
    const int tile = blockIdx.x;

    gather4(featb2, row_ptr, sorted_src, (tile << 4) + (wv << 2), l, mt, wv << 2);
    __syncthreads();

    const int col = l & 15;
    const int g   = l >> 4;
    bf16x8 af0 = *(const bf16x8*)&mt[col][g << 3];
    bf16x8 af1 = *(const bf16x8*)&mt[col][32 + (g << 3)];
    const unsigned int* srw = (const unsigned int*)featb2 + ((tile << 4) + col) * 32;
    bf16x8 af2 = *(const bf16x8*)(srw + (g << 2));
    bf16x8 af3 = *(const bf16x8*)(srw + 16 + (g << 2));

    const int n = wv;
    bf16x8 b0 = *(const bf16x8*)(packedB + (((0 * 4 + n) * 64 + l) << 2));
    bf16x8 b1 = *(const bf16x8*)(packedB + (((1 * 4 + n) * 64 + l) << 2));
    bf16x8 b2 = *(const bf16x8*)(packedB + (((2 * 4 + n) * 64 + l) << 2));
    bf16x8 b3 = *(const bf16x8*)(packedB + (((3 * 4 + n) * 64 + l) << 2));
    f32x4 a = {0.f, 0.f, 0.f, 0.f};
    a = __builtin_amdgcn_mfma_f32_16x16x32_bf16(af0, b0, a, 0, 0, 0);
    a = __builtin_amdgcn_mfma_f32_16x16x32_bf16(af1, b1, a, 0, 0, 0);
    a = __builtin_amdgcn_mfma_f32_16x16x32_bf16(af2, b2, a, 0, 0, 0);
    a = __builtin_amdgcn_mfma_f32_16x16x32_bf16(af3, b3, a, 0, 0, 0);

    const int j = (n << 4) | col;
    const float bj = bias[j];
#pragma unroll
    for (int r = 0; r < 4; ++r)
        ht[(g << 2) + r][j] = f2bf(fmaxf(a[r] + bj, 0.f));
    __syncthreads();

    if (wv == 0) {   // wave 0 projects the tile
        bf16x8 bo0 = *(const bf16x8*)(packedBo + (l << 2));
        bf16x8 bo1 = *(const bf16x8*)(packedBo + ((64 + l) << 2));
        bf16x8 ha0 = *(const bf16x8*)&ht[col][g << 3];
        bf16x8 ha1 = *(const bf16x8*)&ht[col][32 + (g << 3)];

        f32x4 acc2 = {0.f, 0.f, 0.f, 0.f};
        acc2 = __builtin_amdgcn_mfma_f32_16x16x32_bf16(ha0, bo0, acc2, 0, 0, 0);
        acc2 = __builtin_amdgcn_mfma_f32_16x16x32_bf16(ha1, bo1, acc2, 0, 0, 0);

        if (col < NCLS) {
            float bj2 = bout[col];
#pragma unroll
            for (int r = 0; r < 4; ++r)
                out[((tile << 4) + (g << 2) + r) * NCLS + col] = acc2[r] + bj2;
        }
    }
}

// ---------------------------------------------------------------------------
extern "C" void kernel_launch(void* const* d_in, const int* in_sizes, int n_in,
                              void* d_out, int out_size, void* d_ws, size_t ws_size,
                              hipStream_t stream) {
    const float* x   = (const float*)d_in[0];
    const int*   ei  = (const int*)d_in[1];   // [2, N_EDGES]
    const int*   src = ei;
    const int*   dst = ei + N_EDGES;
    const float* W1l = (const float*)d_in[2];
    const float* W1r = (const float*)d_in[3];
    const float* b1  = (const float*)d_in[4];
    const float* W2l = (const float*)d_in[5];
    const float* W2r = (const float*)d_in[6];
    const float* b2  = (const float*)d_in[7];
    const float* Wo  = (const float*)d_in[8];
    const float* bo  = (const float*)d_in[9];
    float* out = (float*)d_out;

    char* ws = (char*)d_ws;
    int*   histG      = (int*)(ws + 0x0000000);  // 50176 ints
    int*   scanP      = (int*)(ws + 0x0040000);  // 196 ints
    int*   ebase      = (int*)(ws + 0x0044000);  // 50176 ints
    int*   row_ptr    = (int*)(ws + 0x0080000);  // 100001 ints
    unsigned int* pairs = (unsigned int*)(ws + 0x0100000);     // 4 MB (packed)
    int*   sorted_src = (int*)(ws + 0x0500000);                // 4 MB (+slack)
    unsigned short* xb  = (unsigned short*)(ws + 0x0900000);   // 12.8 MB + zero row
    unsigned short* h1b = (unsigned short*)(ws + 0x1540000);   // 12.8 MB + zero row
    unsigned int* packedB1 = (unsigned int*)(ws + 0x2180000);  // 16 KB
    unsigned int* packedB2 = (unsigned int*)(ws + 0x2184000);  // 16 KB
    unsigned int* packedBo = (unsigned int*)(ws + 0x2188000);  // 2 KB

    const int layer_blocks = NTILES;                   // 6250, exact
    const int hp_blocks    = P_BLOCKS + CVT_BLOCKS + 32 + 2 + 1;  // 6541

    // ---- CSR build + prep (5 dispatches) ----
    hist_prep<<<hp_blocks, 256, 0, stream>>>(dst, histG, x, W1l, W1r, W2l, W2r,
                                             Wo, xb, h1b, packedB1, packedB2,
                                             packedBo);
    scan_partials<<<NBUCK, 256, 0, stream>>>(histG, scanP);
    scan_final<<<NBUCK, 256, 0, stream>>>(histG, scanP, ebase);
    edge_partition<<<P_BLOCKS, 256, 0, stream>>>(src, dst, ebase, pairs);
    bucket_csr<<<NBUCK, 256, 0, stream>>>(pairs, ebase, row_ptr, sorted_src);

    // ---- layer 1 (fused gather+MFMA, 4 waves/tile) ----
    sage_fused<<<layer_blocks, 256, 0, stream>>>((const uint2*)xb, row_ptr,
                                                 sorted_src, packedB1, b1, h1b);

    // ---- layer 2 + output projection (fused) ----
    sage_fused_out<<<layer_blocks, 256, 0, stream>>>((const uint2*)h1b, row_ptr,
                                                     sorted_src, packedB2, b2,
                                                     packedBo, bo, out);
}